// Round 6
// baseline (124.082 us; speedup 1.0000x reference)
//
#include <hip/hip_runtime.h>
#include <math.h>

#define BTILE 1024
#define SEG   128          // BTILE / 8 segments
// 256 threads/block: slot = tid&31 (A-slot), sp = tid>>5 (B-segment 0..7)
// Each thread owns 2 A-points (slot, slot+32) -> 64 A-points per block.
// min_b |a-b|^2 = a2 + min_b (b2 - 2 a.b); LDS planes {-2bx,-2by,-2bz,b2}.

template<bool A_PLANAR, bool B_PLANAR>
__device__ __forceinline__ float chamfer_block(
    const float* __restrict__ A, int An,
    const float* __restrict__ B, int Bn,
    int lbid, float scale,
    float (&sb)[4][BTILE], float (&red)[512])
{
    const int bpb   = An >> 6;           // blocks per batch (An/64)
    const int batch = lbid / bpb;
    const int ablk  = lbid % bpb;
    const float* __restrict__ Ab = A + (size_t)batch * 3 * An;
    const float* __restrict__ Bb = B + (size_t)batch * 3 * Bn;

    const int tid  = threadIdx.x;
    const int slot = tid & 31;
    const int sp   = tid >> 5;
    const int p0   = ablk * 64 + slot;
    const int p1   = p0 + 32;

    float a0x, a0y, a0z, a1x, a1y, a1z;
    if (A_PLANAR) {
        a0x = Ab[p0];   a0y = Ab[An + p0];   a0z = Ab[2*An + p0];
        a1x = Ab[p1];   a1y = Ab[An + p1];   a1z = Ab[2*An + p1];
    } else {
        a0x = Ab[3*p0]; a0y = Ab[3*p0 + 1];  a0z = Ab[3*p0 + 2];
        a1x = Ab[3*p1]; a1y = Ab[3*p1 + 1];  a1z = Ab[3*p1 + 2];
    }
    const float a0s = fmaf(a0x, a0x, fmaf(a0y, a0y, a0z * a0z));
    const float a1s = fmaf(a1x, a1x, fmaf(a1y, a1y, a1z * a1z));

    const float BIG = 3.402823466e38f;
    float n00 = BIG, n01 = BIG, n10 = BIG, n11 = BIG;

    const int NT = Bn / BTILE;
    for (int t = 0; t < NT; ++t) {
        const int t0 = t * BTILE;
        for (int k = tid; k < BTILE; k += 256) {
            float x, y, z;
            if (B_PLANAR) {
                x = Bb[t0 + k]; y = Bb[Bn + t0 + k]; z = Bb[2*Bn + t0 + k];
            } else {
                int base = 3 * (t0 + k);
                x = Bb[base]; y = Bb[base + 1]; z = Bb[base + 2];
            }
            sb[0][k] = -2.0f * x;
            sb[1][k] = -2.0f * y;
            sb[2][k] = -2.0f * z;
            sb[3][k] = fmaf(x, x, fmaf(y, y, z * z));
        }
        __syncthreads();

        const float4* __restrict__ px = (const float4*)&sb[0][sp * SEG];
        const float4* __restrict__ py = (const float4*)&sb[1][sp * SEG];
        const float4* __restrict__ pz = (const float4*)&sb[2][sp * SEG];
        const float4* __restrict__ pw = (const float4*)&sb[3][sp * SEG];
#pragma unroll 2
        for (int g = 0; g < SEG / 4; ++g) {
            float4 x = px[g], y = py[g], z = pz[g], w = pw[g];
            float d0, d1, d2, d3;
            d0 = fmaf(a0x, x.x, fmaf(a0y, y.x, fmaf(a0z, z.x, w.x)));
            d1 = fmaf(a0x, x.y, fmaf(a0y, y.y, fmaf(a0z, z.y, w.y)));
            d2 = fmaf(a0x, x.z, fmaf(a0y, y.z, fmaf(a0z, z.z, w.z)));
            d3 = fmaf(a0x, x.w, fmaf(a0y, y.w, fmaf(a0z, z.w, w.w)));
            n00 = fminf(fminf(d0, d1), n00);      // -> v_min3_f32
            n01 = fminf(fminf(d2, d3), n01);
            d0 = fmaf(a1x, x.x, fmaf(a1y, y.x, fmaf(a1z, z.x, w.x)));
            d1 = fmaf(a1x, x.y, fmaf(a1y, y.y, fmaf(a1z, z.y, w.y)));
            d2 = fmaf(a1x, x.z, fmaf(a1y, y.z, fmaf(a1z, z.z, w.z)));
            d3 = fmaf(a1x, x.w, fmaf(a1y, y.w, fmaf(a1z, z.w, w.w)));
            n10 = fminf(fminf(d0, d1), n10);
            n11 = fminf(fminf(d2, d3), n11);
        }
        __syncthreads();
    }

    // min across the 8 sp-segments, per A-slot
    red[sp * 32 + slot]       = fminf(n00, n01);
    red[256 + sp * 32 + slot] = fminf(n10, n11);
    __syncthreads();
#pragma unroll
    for (int st = 4; st > 0; st >>= 1) {
        if (sp < st) {
            red[sp*32 + slot]       = fminf(red[sp*32 + slot],       red[(sp+st)*32 + slot]);
            red[256 + sp*32 + slot] = fminf(red[256 + sp*32 + slot], red[256 + (sp+st)*32 + slot]);
        }
        __syncthreads();
    }

    float contrib = 0.0f;
    if (tid < 32) {
        float d = fmaxf(0.0f, a0s + red[slot]) + fmaxf(0.0f, a1s + red[256 + slot]);
        d *= scale;
#pragma unroll
        for (int off = 16; off > 0; off >>= 1) d += __shfl_down(d, off, 32);
        contrib = d;   // valid in lane/tid 0
    }
    return contrib;
}

__device__ __forceinline__ float kp_block(const float* __restrict__ a,
                                          const float* __restrict__ b, int n,
                                          float (&red)[512])
{
    int tid = threadIdx.x;
    float s = 0.0f;
    for (int i = tid; i < n; i += 256) {
        float d = a[i] - b[i];
        s = fmaf(d, d, s);
    }
    for (int off = 32; off > 0; off >>= 1) s += __shfl_down(s, off, 64);
    if ((tid & 63) == 0) red[tid >> 6] = s;
    __syncthreads();
    float r = 0.0f;
    if (tid == 0) r = (red[0] + red[1] + red[2] + red[3]) / (float)n;
    return r;
}

// ws layout (bytes): [0..3] acc float, [16..19] done-counter uint. memset(0,64) first.
__global__ __launch_bounds__(256, 8) void fused_all(
    const float* __restrict__ pred, const float* __restrict__ target, int nkp,
    const float* __restrict__ coarse, int Nc,
    const float* __restrict__ fine, int Nf,
    const float* __restrict__ gt, int M,
    int r1, int r2, int r3, int r4,
    float sc_f1, float sc_f2, float sc_c1, float sc_c2,
    float* __restrict__ ws, float* __restrict__ out)
{
    __shared__ __align__(16) float sb[4][BTILE];
    __shared__ float red[512];
    const int bid = blockIdx.x;
    const int nb  = gridDim.x;

    float contrib;
    // long (4-tile) scans first, short c2 scans last, kp at the very end
    if (bid < r1)
        contrib = chamfer_block<true,  false>(fine,   Nf, gt,     M,  bid,      sc_f1, sb, red);
    else if (bid < r2)
        contrib = chamfer_block<false, true >(gt,     M,  fine,   Nf, bid - r1, sc_f2, sb, red);
    else if (bid < r3)
        contrib = chamfer_block<true,  false>(coarse, Nc, gt,     M,  bid - r2, sc_c1, sb, red);
    else if (bid < r4)
        contrib = chamfer_block<false, true >(gt,     M,  coarse, Nc, bid - r3, sc_c2, sb, red);
    else
        contrib = kp_block(pred, target, nkp, red);

    if (threadIdx.x == 0) {
        atomicAdd(ws, contrib);                     // device-scope f32 atomic
        __threadfence();
        unsigned old = atomicAdd((unsigned*)ws + 4, 1u);
        if (old == (unsigned)(nb - 1)) {            // last block done
            __threadfence();
            out[0] = atomicAdd(ws, 0.0f);           // coherent read of final sum
        }
    }
}

extern "C" void kernel_launch(void* const* d_in, const int* in_sizes, int n_in,
                              void* d_out, int out_size, void* d_ws, size_t ws_size,
                              hipStream_t stream) {
    const float* pred   = (const float*)d_in[0];
    const float* target = (const float*)d_in[1];
    const float* coarse = (const float*)d_in[2]; // [B,3,Nc]
    const float* fine   = (const float*)d_in[3]; // [B,3,Nf]
    const float* gt     = (const float*)d_in[4]; // [B,M,3]
    float* out = (float*)d_out;
    float* ws  = (float*)d_ws;

    const int nkp = in_sizes[0];            // 240
    const int B   = nkp / 30;               // 8
    const int Nc  = in_sizes[2] / (3 * B);  // 1024
    const int Nf  = in_sizes[3] / (3 * B);  // 4096
    const int M   = in_sizes[4] / (3 * B);  // 4096

    const int nb_f1 = B * (Nf / 64);        // 512
    const int nb_f2 = B * (M  / 64);        // 512
    const int nb_c1 = B * (Nc / 64);        // 128
    const int nb_c2 = B * (M  / 64);        // 512
    const int r1 = nb_f1;
    const int r2 = r1 + nb_f2;
    const int r3 = r2 + nb_c1;
    const int r4 = r3 + nb_c2;
    const int nb = r4 + 1;                  // +1 kp block -> 1665

    hipMemsetAsync(ws, 0, 64, stream);      // acc + counter
    fused_all<<<nb, 256, 0, stream>>>(
        pred, target, nkp, coarse, Nc, fine, Nf, gt, M,
        r1, r2, r3, r4,
        1.0f / (B * Nf), 1.0f / (B * M), 1.0f / (B * Nc), 1.0f / (B * M),
        ws, out);
}